// Round 12
// baseline (563.111 us; speedup 1.0000x reference)
//
#include <hip/hip_runtime.h>

// ODE-RNN via MFMA. r5 skeleton restructured to fit TWO blocks per CU
// (independent barrier domains -> stall overlap):
//  - W2 matrices (f2/z2/r2/h2) moved to LDS as W2T[64][128] bf16 (272B pitch),
//    read as B-fragments; W1 stays in VGPRs (14 frags = 56 regs)
//  - __launch_bounds__(512,4) caps VGPR at 128 -> 4 waves/SIMD = 2 blocks/CU
//  - activation buffers compacted to 8 rows (A-frag row = lane&7, broadcast
//    copies for lanes 32-63; epilogue stores guarded lane<32)
//  - f1-hidden and h1-hidden share one buffer (disjoint live ranges)
//  - deferred out_ys stores (r11)
// 256 blocks x 512 threads (8 waves); NT=8 trajs/block.
// Fragment mapping (16x16x32 bf16): A: lane l -> A[l&15][kt*32+(l>>4)*8+j],
// B: lane l -> B[kt*32+(l>>4)*8+j][l&15], C/D: col=l&15, row=(l>>4)*4+reg.

#define NBT   2048
#define TSTEP 200
#define NT    8

typedef short s8v __attribute__((ext_vector_type(8)));   // 8 bf16 (4 VGPRs)
typedef float f4v __attribute__((ext_vector_type(4)));

// pitches: (pitch/4)%32==4 -> row-base bank 4r mod 32 -> <=2-way (free)
#define RB_W 272    // W2T [64][128] bf16 (+pad; k>=100 zeroed -> no NaN via A*0)
#define RB_Y 144    // y  [8][64]  bf16
#define RB_C 272    // c  [8][128] bf16; also pitch for hidden buffers
#define OFF_WF2 0
#define OFF_WZ2 17408
#define OFF_WR2 34816
#define OFF_WH2 52224
#define OFF_Y   69632
#define OFF_C   70784
#define OFF_HFH 72960   // f1-hidden (P1->P2) reused for h1-hidden (P5->P6)
#define OFF_HZ  75136
#define OFF_HR  77312
#define SMEM_TOT 79488

__device__ __forceinline__ unsigned cvtpk(float lo, float hi) {
    unsigned r;
    asm("v_cvt_pk_bf16_f32 %0, %1, %2" : "=v"(r) : "v"(lo), "v"(hi));
    return r;
}
__device__ __forceinline__ unsigned short f2bf(float f) {  // staging only
    unsigned int b = __float_as_uint(f);
    return (unsigned short)((b + 0x7fffu + ((b >> 16) & 1u)) >> 16);
}
__device__ __forceinline__ float bf2f(unsigned short u) {
    return __uint_as_float(((unsigned)u) << 16);
}
__device__ __forceinline__ float tanh_f(float x) {
    float e = __expf(2.0f * x);
    return fmaf(-2.0f, __builtin_amdgcn_rcpf(e + 1.0f), 1.0f);
}
__device__ __forceinline__ float sigm_f(float x) {
    return __builtin_amdgcn_rcpf(1.0f + __expf(-x));
}
__device__ __forceinline__ f4v mfma16(s8v a, s8v b, f4v c) {
    return __builtin_amdgcn_mfma_f32_16x16x32_bf16(a, b, c, 0, 0, 0);
}
__device__ __forceinline__ f4v splat(float b) { f4v v = {b, b, b, b}; return v; }

// W1 B-fragment from global: lane holds W[k0+j][n] j=0..7 (zero-padded)
__device__ __forceinline__ s8v load_bfrag(const float* __restrict__ W,
                                          int Ncols, int Krows, int k0, int n) {
    s8v r;
#pragma unroll
    for (int j = 0; j < 8; ++j) {
        const int k = k0 + j;
        const float v = (k < Krows && n < Ncols) ? W[k * Ncols + n] : 0.0f;
        r[j] = (short)f2bf(v);
    }
    return r;
}

// A-fragment from 8-row buffer: row = lane&7 (rows 8-15 = broadcast copies)
template <int RB>
__device__ __forceinline__ s8v load_af(const char* base, int lane, int kt) {
    return *(const s8v*)(base + (lane & 7) * RB + ((lane >> 4) * 16) + kt * 64);
}
// W2 B-fragment from LDS: lane l -> W2T row tw2*16+(l&15), k = kt*32+(l>>4)*8
__device__ __forceinline__ s8v load_bf(const char* base, int tile, int lane, int kt) {
    return *(const s8v*)(base + (tile * 16 + (lane & 15)) * RB_W +
                         ((lane >> 4) * 16) + kt * 64);
}

// write 4 fp32 values (rows rb..rb+3, one col) as bf16; caller guards lane<32
__device__ __forceinline__ void store4(char* base, int col2, int rb, int pitch,
                                       float v0, float v1, float v2, float v3) {
    const unsigned u01 = cvtpk(v0, v1), u23 = cvtpk(v2, v3);
    *(short*)(base + (rb + 0) * pitch + col2) = (short)(u01 & 0xffffu);
    *(short*)(base + (rb + 1) * pitch + col2) = (short)(u01 >> 16);
    *(short*)(base + (rb + 2) * pitch + col2) = (short)(u23 & 0xffffu);
    *(short*)(base + (rb + 3) * pitch + col2) = (short)(u23 >> 16);
}
__device__ __forceinline__ void store_tanh(char* base, int n0, int lane, f4v a) {
    if (lane < 32)   // rows 0-7 only (8-row buffers)
        store4(base, (n0 + (lane & 15)) * 2, (lane >> 4) * 4, RB_C,
               tanh_f(a[0]), tanh_f(a[1]), tanh_f(a[2]), tanh_f(a[3]));
}

// stage W2 [100][64] fp32 -> W2T LDS [64 rows][k] bf16 (pad pre-zeroed)
__device__ void stage_w2t(const float* __restrict__ W, char* __restrict__ dst,
                          int tid) {
    for (int idx = tid; idx < 6400; idx += 512) {
        const int k = idx >> 6, n = idx & 63;
        *(unsigned short*)(dst + n * RB_W + k * 2) = f2bf(W[idx]);
    }
}

__global__ __launch_bounds__(512, 4) void ode_rnn_2b(
    const float* __restrict__ data, const float* __restrict__ tsv,
    const float* __restrict__ Wf1, const float* __restrict__ bf1,
    const float* __restrict__ Wf2, const float* __restrict__ bf2,
    const float* __restrict__ Wz1, const float* __restrict__ bz1,
    const float* __restrict__ Wz2, const float* __restrict__ bz2,
    const float* __restrict__ Wr1, const float* __restrict__ br1,
    const float* __restrict__ Wr2, const float* __restrict__ br2,
    const float* __restrict__ Wh1, const float* __restrict__ bh1,
    const float* __restrict__ Wh2, const float* __restrict__ bh2,
    float* __restrict__ out_yi, float* __restrict__ out_ys)
{
    extern __shared__ __align__(16) char smem[];

    const int tid  = threadIdx.x;
    const int lane = tid & 63;
    const int wv   = tid >> 6;          // 0..7
    const bool isA = (wv < 4);          // state-carrying waves
    const int b0   = blockIdx.x * NT;

    // zero ALL of LDS once (W2T pad must be 0: bf16 garbage*0 can be NaN)
    for (int i = tid; i < SMEM_TOT / 4; i += 512) ((unsigned*)smem)[i] = 0u;
    __syncthreads();
    stage_w2t(Wf2, smem + OFF_WF2, tid);
    stage_w2t(Wz2, smem + OFF_WZ2, tid);
    stage_w2t(Wr2, smem + OFF_WR2, tid);
    stage_w2t(Wh2, smem + OFF_WH2, tid);

    // ---- W1 B-fragments in VGPRs (14 frags = 56 regs) ----
    const int kb = (lane >> 4) * 8;
    const int n1 = wv * 16 + (lane & 15);          // W1 tile wv (cols 0..127)
    const int tw2 = wv & 3;                        // W2 tile
    const int n2  = tw2 * 16 + (lane & 15);        // W2 out col (0..63)

    s8v Bf1[2], Bz1[4], Br1[4], Bh1[4];
#pragma unroll
    for (int kt = 0; kt < 2; ++kt)
        Bf1[kt] = load_bfrag(Wf1, 100, 64, kt * 32 + kb, n1);
#pragma unroll
    for (int kt = 0; kt < 4; ++kt) {
        Bz1[kt] = load_bfrag(Wz1, 100, 128, kt * 32 + kb, n1);
        Br1[kt] = load_bfrag(Wr1, 100, 128, kt * 32 + kb, n1);
        Bh1[kt] = load_bfrag(Wh1, 100, 128, kt * 32 + kb, n1);
    }

    const float b1f = (n1 < 100) ? bf1[n1] : 0.0f;
    const float b1z = (n1 < 100) ? bz1[n1] : 0.0f;
    const float b1r = (n1 < 100) ? br1[n1] : 0.0f;
    const float b1h = (n1 < 100) ? bh1[n1] : 0.0f;
    const float bF2 = isA ? bf2[n2] : 0.0f;
    const float bZ2 = isA ? bz2[n2] : 0.0f;
    const float bH2 = isA ? bh2[n2] : 0.0f;
    const float bR2 = isA ? 0.0f : br2[n2];

    // x staging (waves 4-7): thread -> (traj, 2 elems)
    const int t2  = tid & 255;
    const int xtr = t2 >> 5;
    const int xd  = (t2 & 31) * 2;

    const int col2 = n2 * 2;            // byte col for W2-output writes
    const int rb   = (lane >> 4) * 4;   // C/D row base
    const int rbm  = rb & 7;            // clamped row base for LDS reads

    f4v y_reg = splat(0.0f), yode = splat(0.0f), zf = splat(0.0f);
    float dt = tsv[1] - tsv[0];
    __syncthreads();

    for (int s = 0; s < TSTEP - 1; ++s) {
        // deferred out_ys store for step s-1 (drains under P1)
        if (isA && s > 0 && lane < 32) {
#pragma unroll
            for (int r = 0; r < 4; ++r)
                out_ys[((size_t)(b0 + rb + r) * (TSTEP - 1) + (s - 1)) * 64 + n2] =
                    y_reg[r];
        }
        float2 xv;
        if (!isA)
            xv = *(const float2*)&data[((size_t)(b0 + xtr) * TSTEP + (s + 1)) * 64 + xd];

        // ---- P1: f1 hidden (all waves, tile wv) ----
        {
            const s8v ya0 = load_af<RB_Y>(smem + OFF_Y, lane, 0);
            const s8v ya1 = load_af<RB_Y>(smem + OFF_Y, lane, 1);
            f4v a = splat(b1f);
            a = mfma16(ya0, Bf1[0], a);
            a = mfma16(ya1, Bf1[1], a);
            store_tanh(smem + OFF_HFH, wv * 16, lane, a);
        }
        __syncthreads();

        // ---- P2: f2 out (w0-3) -> yode -> c[:, :64]; x -> c[:, 64:] (w4-7) ----
        if (isA) {
            f4v ac = splat(bF2);
#pragma unroll
            for (int kt = 0; kt < 4; ++kt)
                ac = mfma16(load_af<RB_C>(smem + OFF_HFH, lane, kt),
                            load_bf(smem + OFF_WF2, tw2, lane, kt), ac);
#pragma unroll
            for (int r = 0; r < 4; ++r) yode[r] = fmaf(dt, ac[r], y_reg[r]);
            if (lane < 32)
                store4(smem + OFF_C, col2, rb, RB_C,
                       yode[0], yode[1], yode[2], yode[3]);
        } else {
            *(unsigned*)(smem + OFF_C + xtr * RB_C + 128 + (t2 & 31) * 4) =
                cvtpk(xv.x, xv.y);
        }
        __syncthreads();

        // ---- P3: z1 + r1 hidden (all waves, tile wv) ----
        {
            const s8v c0 = load_af<RB_C>(smem + OFF_C, lane, 0);
            const s8v c1 = load_af<RB_C>(smem + OFF_C, lane, 1);
            const s8v c2 = load_af<RB_C>(smem + OFF_C, lane, 2);
            const s8v c3 = load_af<RB_C>(smem + OFF_C, lane, 3);
            f4v az = splat(b1z), ar = splat(b1r);
            az = mfma16(c0, Bz1[0], az); az = mfma16(c1, Bz1[1], az);
            az = mfma16(c2, Bz1[2], az); az = mfma16(c3, Bz1[3], az);
            ar = mfma16(c0, Br1[0], ar); ar = mfma16(c1, Br1[1], ar);
            ar = mfma16(c2, Br1[2], ar); ar = mfma16(c3, Br1[3], ar);
            store_tanh(smem + OFF_HZ, wv * 16, lane, az);
            store_tanh(smem + OFF_HR, wv * 16, lane, ar);
        }
        __syncthreads();

        // ---- P4: z2 (w0-3, zf in regs) | r2 (w4-7) + ch=yode*r in-place ----
        if (isA) {
            f4v az = splat(bZ2);
#pragma unroll
            for (int kt = 0; kt < 4; ++kt)
                az = mfma16(load_af<RB_C>(smem + OFF_HZ, lane, kt),
                            load_bf(smem + OFF_WZ2, tw2, lane, kt), az);
#pragma unroll
            for (int r = 0; r < 4; ++r) zf[r] = sigm_f(az[r]);
        } else {
            unsigned short yv[4];
#pragma unroll
            for (int r = 0; r < 4; ++r)
                yv[r] = *(const unsigned short*)
                    (smem + OFF_C + (rbm + r) * RB_C + col2);
            f4v ar = splat(bR2);
#pragma unroll
            for (int kt = 0; kt < 4; ++kt)
                ar = mfma16(load_af<RB_C>(smem + OFF_HR, lane, kt),
                            load_bf(smem + OFF_WR2, tw2, lane, kt), ar);
            float ch[4];
#pragma unroll
            for (int r = 0; r < 4; ++r)
                ch[r] = bf2f(yv[r]) * sigm_f(ar[r]);
            if (lane < 32)
                store4(smem + OFF_C, col2, rb, RB_C, ch[0], ch[1], ch[2], ch[3]);
        }
        __syncthreads();

        // ---- P5: h1 hidden (all waves, tile wv) -> HFH (reused) ----
        {
            const s8v d0 = load_af<RB_C>(smem + OFF_C, lane, 0);
            const s8v d1 = load_af<RB_C>(smem + OFF_C, lane, 1);
            const s8v d2 = load_af<RB_C>(smem + OFF_C, lane, 2);
            const s8v d3 = load_af<RB_C>(smem + OFF_C, lane, 3);
            f4v ah = splat(b1h);
            ah = mfma16(d0, Bh1[0], ah); ah = mfma16(d1, Bh1[1], ah);
            ah = mfma16(d2, Bh1[2], ah); ah = mfma16(d3, Bh1[3], ah);
            store_tanh(smem + OFF_HFH, wv * 16, lane, ah);
        }
        __syncthreads();

        // ---- P6: h2 out (w0-3); y = (1-z)*h + z*yode; y -> LDS ----
        if (isA) {
            f4v ah = splat(bH2);
#pragma unroll
            for (int kt = 0; kt < 4; ++kt)
                ah = mfma16(load_af<RB_C>(smem + OFF_HFH, lane, kt),
                            load_bf(smem + OFF_WH2, tw2, lane, kt), ah);
#pragma unroll
            for (int r = 0; r < 4; ++r) {
                const float h = tanh_f(ah[r]);
                y_reg[r] = (1.0f - zf[r]) * h + zf[r] * yode[r];
            }
            if (lane < 32)
                store4(smem + OFF_Y, col2, rb, RB_Y,
                       y_reg[0], y_reg[1], y_reg[2], y_reg[3]);
        }
        dt = tsv[s] - tsv[s + 1];
        __syncthreads();
    }

    // final flush: out_ys step 198 + out_yi
    if (isA && lane < 32) {
#pragma unroll
        for (int r = 0; r < 4; ++r) {
            out_ys[((size_t)(b0 + rb + r) * (TSTEP - 1) + (TSTEP - 2)) * 64 + n2] =
                y_reg[r];
            out_yi[(size_t)(b0 + rb + r) * 64 + n2] = y_reg[r];
        }
    }
}

extern "C" void kernel_launch(void* const* d_in, const int* in_sizes, int n_in,
                              void* d_out, int out_size, void* d_ws, size_t ws_size,
                              hipStream_t stream) {
    const float* data = (const float*)d_in[0];
    const float* tsv  = (const float*)d_in[1];
    const float* Wf1 = (const float*)d_in[2];  const float* bf1 = (const float*)d_in[3];
    const float* Wf2 = (const float*)d_in[4];  const float* bf2 = (const float*)d_in[5];
    const float* Wz1 = (const float*)d_in[6];  const float* bz1 = (const float*)d_in[7];
    const float* Wz2 = (const float*)d_in[8];  const float* bz2 = (const float*)d_in[9];
    const float* Wr1 = (const float*)d_in[10]; const float* br1 = (const float*)d_in[11];
    const float* Wr2 = (const float*)d_in[12]; const float* br2 = (const float*)d_in[13];
    const float* Wh1 = (const float*)d_in[14]; const float* bh1 = (const float*)d_in[15];
    const float* Wh2 = (const float*)d_in[16]; const float* bh2 = (const float*)d_in[17];

    float* out_yi = (float*)d_out;
    float* out_ys = out_yi + (size_t)NBT * 64;

    (void)hipFuncSetAttribute((const void*)ode_rnn_2b,
                              hipFuncAttributeMaxDynamicSharedMemorySize, SMEM_TOT);

    ode_rnn_2b<<<NBT / NT, 512, SMEM_TOT, stream>>>(
        data, tsv, Wf1, bf1, Wf2, bf2, Wz1, bz1, Wz2, bz2,
        Wr1, br1, Wr2, br2, Wh1, bh1, Wh2, bh2, out_yi, out_ys);
}